// Round 1
// baseline (5104.444 us; speedup 1.0000x reference)
//
#include <hip/hip_runtime.h>
#include <hip/hip_bf16.h>

typedef __attribute__((ext_vector_type(8))) short bf8_t;
typedef __attribute__((ext_vector_type(4))) float f4_t;

#define DEV static __device__ __forceinline__

DEV short f2bf(float x){
  unsigned u = __float_as_uint(x);
  u += 0x7fffu + ((u >> 16) & 1u);
  return (short)(u >> 16);
}
DEV float bf2f(short h){
  return __uint_as_float(((unsigned)(unsigned short)h) << 16);
}

// C = act(A @ W.T + bias) [* scale] [+ res]
// A: (M,K) f32 row-major, row stride lda
// W: (N,K) f32 row-major, row stride ldw
// SPLIT: bf16x2 split-precision (3 MFMAs) for ~fp32 accuracy
// ACT: 0 none, 1 relu, 2 leaky-relu(0.01)
template<int ACT, bool SPLIT>
__global__ __launch_bounds__(256, 2)
void gemm_k(const float* __restrict__ A, int lda,
            const float* __restrict__ W, int ldw,
            const float* __restrict__ bias, int posbias,
            const float* __restrict__ res, int ldres,
            const float* __restrict__ scale, int sstr,
            float* __restrict__ D, int ldd, int K)
{
  constexpr int NS = SPLIT ? 2 : 1;
  __shared__ short As[NS][128][40];   // +8 pad: bank-conflict-free b128 reads
  __shared__ short Bs[NS][128][40];

  const int tid  = threadIdx.x;
  const int lane = tid & 63;
  const int wid  = tid >> 6;
  const int wr = wid >> 1, wc = wid & 1;   // 2x2 waves, 64x64 each
  const int fr = lane & 15;
  const int kg = lane >> 4;

  f4_t acc[4][4];
#pragma unroll
  for(int m=0;m<4;m++)
#pragma unroll
    for(int n=0;n<4;n++)
#pragma unroll
      for(int j=0;j<4;j++) acc[m][n][j] = 0.f;

  const int srow  = tid >> 1;        // 0..127
  const int skoff = (tid & 1) << 4;  // 0 or 16
  const float* pA = A + (size_t)((size_t)blockIdx.y*128 + srow)*lda + skoff;
  const float* pW = W + (size_t)((size_t)blockIdx.x*128 + srow)*ldw + skoff;

  for(int kb=0; kb<K; kb+=32){
    float va[16], vw[16];
    {
      const f4_t* a4 = (const f4_t*)(pA + kb);
      const f4_t* w4 = (const f4_t*)(pW + kb);
#pragma unroll
      for(int q=0;q<4;q++){
        f4_t ta = a4[q], tw = w4[q];
#pragma unroll
        for(int j=0;j<4;j++){ va[q*4+j] = ta[j]; vw[q*4+j] = tw[j]; }
      }
    }
    __syncthreads();  // previous iter's LDS reads done before overwrite
#pragma unroll
    for(int h=0; h<2; h++){
      bf8_t ha, hw;
#pragma unroll
      for(int j=0;j<8;j++){ ha[j] = f2bf(va[h*8+j]); hw[j] = f2bf(vw[h*8+j]); }
      *(bf8_t*)&As[0][srow][skoff + h*8] = ha;
      *(bf8_t*)&Bs[0][srow][skoff + h*8] = hw;
      if(SPLIT){
        bf8_t la, lw;
#pragma unroll
        for(int j=0;j<8;j++){
          la[j] = f2bf(va[h*8+j] - bf2f(ha[j]));
          lw[j] = f2bf(vw[h*8+j] - bf2f(hw[j]));
        }
        *(bf8_t*)&As[NS-1][srow][skoff + h*8] = la;
        *(bf8_t*)&Bs[NS-1][srow][skoff + h*8] = lw;
      }
    }
    __syncthreads();

    bf8_t a0[4], b0[4], a1[4], b1[4];
#pragma unroll
    for(int m=0;m<4;m++){
      a0[m] = *(const bf8_t*)&As[0][wr*64 + m*16 + fr][kg*8];
      if(SPLIT) a1[m] = *(const bf8_t*)&As[NS-1][wr*64 + m*16 + fr][kg*8];
    }
#pragma unroll
    for(int n=0;n<4;n++){
      b0[n] = *(const bf8_t*)&Bs[0][wc*64 + n*16 + fr][kg*8];
      if(SPLIT) b1[n] = *(const bf8_t*)&Bs[NS-1][wc*64 + n*16 + fr][kg*8];
    }
#pragma unroll
    for(int m=0;m<4;m++)
#pragma unroll
      for(int n=0;n<4;n++){
        acc[m][n] = __builtin_amdgcn_mfma_f32_16x16x32_bf16(a0[m], b0[n], acc[m][n], 0,0,0);
        if(SPLIT){
          acc[m][n] = __builtin_amdgcn_mfma_f32_16x16x32_bf16(a0[m], b1[n], acc[m][n], 0,0,0);
          acc[m][n] = __builtin_amdgcn_mfma_f32_16x16x32_bf16(a1[m], b0[n], acc[m][n], 0,0,0);
        }
      }
  }

  const int Ncols = (int)gridDim.x * 128;
  const int rbase = blockIdx.y*128 + wr*64;
  const int cbase = blockIdx.x*128 + wc*64;
#pragma unroll
  for(int m=0;m<4;m++){
#pragma unroll
    for(int n=0;n<4;n++){
      const int col = cbase + n*16 + fr;
#pragma unroll
      for(int j=0;j<4;j++){
        const int row = rbase + m*16 + kg*4 + j;
        float v = acc[m][n][j];
        if(bias) v += bias[posbias ? ((row & 1) * Ncols + col) : col];
        if(ACT == 1) v = fmaxf(v, 0.f);
        if(ACT == 2) v = (v >= 0.f) ? v : 0.01f * v;
        if(scale) v *= scale[(size_t)row * sstr];
        if(res)   v += res[(size_t)row * ldres + col];
        D[(size_t)row * ldd + col] = v;
      }
    }
  }
}

// LayerNorm over last dim 512: y = (x-m)/sqrt(v+eps)*s + b. One wave per row.
__global__ __launch_bounds__(256)
void ln_k(const float* __restrict__ x, int ldx,
          const float* __restrict__ s, const float* __restrict__ b,
          float* __restrict__ y, int ldy)
{
  const int lane = threadIdx.x & 63;
  const int row = blockIdx.x*4 + (threadIdx.x >> 6);
  const float* xr = x + (size_t)row * ldx + lane*8;
  f4_t v0 = *(const f4_t*)xr;
  f4_t v1 = *(const f4_t*)(xr + 4);
  float sum = (v0[0]+v0[1])+(v0[2]+v0[3])+((v1[0]+v1[1])+(v1[2]+v1[3]));
#pragma unroll
  for(int o=32;o;o>>=1) sum += __shfl_xor(sum, o, 64);
  const float mean = sum * (1.f/512.f);
  float vs = 0.f;
#pragma unroll
  for(int j=0;j<4;j++){ float d0=v0[j]-mean, d1=v1[j]-mean; vs += d0*d0 + d1*d1; }
#pragma unroll
  for(int o=32;o;o>>=1) vs += __shfl_xor(vs, o, 64);
  const float rstd = rsqrtf(vs*(1.f/512.f) + 1e-5f);
  float* yr = y + (size_t)row*ldy + lane*8;
  const float* sp = s + lane*8; const float* bp = b + lane*8;
  f4_t o0, o1;
#pragma unroll
  for(int j=0;j<4;j++){
    o0[j] = (v0[j]-mean)*rstd*sp[j]   + bp[j];
    o1[j] = (v1[j]-mean)*rstd*sp[j+4] + bp[j+4];
  }
  *(f4_t*)yr = o0;
  *(f4_t*)(yr+4) = o1;
}

// logits = R1 @ r2w.T + r2b (f32, K=256, E=8); top-2 softmax -> dense gates (B,8)
__global__ __launch_bounds__(256)
void router_k(const float* __restrict__ R1,
              const float* __restrict__ r2w, const float* __restrict__ r2b,
              float* __restrict__ gates)
{
  const int lane = threadIdx.x & 63;
  const int row = blockIdx.x*4 + (threadIdx.x >> 6);
  f4_t xv = *(const f4_t*)(R1 + (size_t)row*256 + lane*4);
  float lg[8];
#pragma unroll
  for(int e=0;e<8;e++){
    f4_t wv = *(const f4_t*)(r2w + e*256 + lane*4);
    float p = xv[0]*wv[0] + xv[1]*wv[1] + xv[2]*wv[2] + xv[3]*wv[3];
#pragma unroll
    for(int o=32;o;o>>=1) p += __shfl_xor(p, o, 64);
    lg[e] = p + r2b[e];
  }
  int i1 = 0; float v1 = lg[0];
#pragma unroll
  for(int e=1;e<8;e++) if(lg[e] > v1){ v1 = lg[e]; i1 = e; }
  int i2 = -1; float v2 = -3.4e38f;
#pragma unroll
  for(int e=0;e<8;e++) if(e != i1 && lg[e] > v2){ v2 = lg[e]; i2 = e; }
  const float p2 = 1.f / (1.f + expf(v1 - v2));
  const float p1 = 1.f - p2;
  if(lane < 8) gates[(size_t)row*8 + lane] = (lane==i1) ? p1 : (lane==i2 ? p2 : 0.f);
}

// bias2[s*512+c] = pib[c] + pos[s*512+c]  (folds pos into input-proj bias)
__global__ void bias2_k(const float* __restrict__ pib, const float* __restrict__ pos,
                        float* __restrict__ bias2)
{
  int i = blockIdx.x*256 + threadIdx.x;
  if(i < 1024) bias2[i] = pib[i & 511] + pos[i];
}

extern "C" void kernel_launch(void* const* d_in, const int* in_sizes, int n_in,
                              void* d_out, int out_size, void* d_ws, size_t ws_size,
                              hipStream_t stream)
{
  (void)in_sizes; (void)n_in; (void)out_size; (void)ws_size;
  const float* src     = (const float*)d_in[0];
  const float* piw     = (const float*)d_in[1];
  const float* pib     = (const float*)d_in[2];
  const float* pos     = (const float*)d_in[3];
  const float* ln1_s   = (const float*)d_in[4];
  const float* ln1_b   = (const float*)d_in[5];
  // ln2 (d_in[6], d_in[7]) is dead: its output only feeds Q, and softmax over 1 key == 1
  const float* ln3_s   = (const float*)d_in[8];
  const float* ln3_b   = (const float*)d_in[9];
  const float* sa_in_w = (const float*)d_in[10];
  const float* sa_in_b = (const float*)d_in[11];
  const float* sa_ow   = (const float*)d_in[12];
  const float* sa_ob   = (const float*)d_in[13];
  const float* ca_in_w = (const float*)d_in[14];
  const float* ca_in_b = (const float*)d_in[15];
  const float* ca_ow   = (const float*)d_in[16];
  const float* ca_ob   = (const float*)d_in[17];
  const float* ff1_w   = (const float*)d_in[18];
  const float* ff1_b   = (const float*)d_in[19];
  const float* ff2_w   = (const float*)d_in[20];
  const float* ff2_b   = (const float*)d_in[21];
  const float* r1_w    = (const float*)d_in[22];
  const float* r1_b    = (const float*)d_in[23];
  const float* r2_w    = (const float*)d_in[24];
  const float* r2_b    = (const float*)d_in[25];
  const float* se1_w   = (const float*)d_in[26];
  const float* se1_b   = (const float*)d_in[27];
  const float* se2_w   = (const float*)d_in[28];
  const float* se2_b   = (const float*)d_in[29];
  const float* se3_w   = (const float*)d_in[30];
  const float* se3_b   = (const float*)d_in[31];
  const float* te1_w   = (const float*)d_in[32];
  const float* te1_b   = (const float*)d_in[33];
  const float* te2_w   = (const float*)d_in[34];
  const float* te2_b   = (const float*)d_in[35];
  const float* te3_w   = (const float*)d_in[36];
  const float* te3_b   = (const float*)d_in[37];
  const float* po_w    = (const float*)d_in[38];
  const float* po_b    = (const float*)d_in[39];
  float* out = (float*)d_out;

  // workspace layout (floats): ~134.5 MB
  float* xbuf  = (float*)d_ws;                  // (B,2,512) interleaved tgt/mem
  float* H     = xbuf + (size_t)16384*512;      // (B,512)
  float* V     = H    + (size_t)8192*512;       // (B,512)
  float* F     = V    + (size_t)8192*512;       // (B,2048) big scratch
  float* F2    = F    + (size_t)8192*1024;      // alias: second half of F
  float* gates = F    + (size_t)8192*2048;      // (B,8)
  float* bias2 = gates + (size_t)8192*8;        // (1024)

  float* tgt = xbuf;        // row stride 1024
  float* mem = xbuf + 512;  // row stride 1024

  auto gemm = [&](int ACT, bool SPLIT, const float* A, int lda, const float* W, int ldw,
                  const float* bias, int posbias, const float* res, int ldres,
                  const float* scale, int sstr, float* D, int ldd, int M, int N, int K){
    dim3 g(N/128, M/128), blk(256);
    if(SPLIT){
      if(ACT==0)      gemm_k<0,true ><<<g,blk,0,stream>>>(A,lda,W,ldw,bias,posbias,res,ldres,scale,sstr,D,ldd,K);
      else if(ACT==1) gemm_k<1,true ><<<g,blk,0,stream>>>(A,lda,W,ldw,bias,posbias,res,ldres,scale,sstr,D,ldd,K);
      else            gemm_k<2,true ><<<g,blk,0,stream>>>(A,lda,W,ldw,bias,posbias,res,ldres,scale,sstr,D,ldd,K);
    } else {
      if(ACT==0)      gemm_k<0,false><<<g,blk,0,stream>>>(A,lda,W,ldw,bias,posbias,res,ldres,scale,sstr,D,ldd,K);
      else if(ACT==1) gemm_k<1,false><<<g,blk,0,stream>>>(A,lda,W,ldw,bias,posbias,res,ldres,scale,sstr,D,ldd,K);
      else            gemm_k<2,false><<<g,blk,0,stream>>>(A,lda,W,ldw,bias,posbias,res,ldres,scale,sstr,D,ldd,K);
    }
  };

  bias2_k<<<dim3(4),dim3(256),0,stream>>>(pib, pos, bias2);

  // input projection: xbuf = src @ piw.T + (pib + pos[row&1])   [split precision]
  gemm(0, true, src, 512, piw, 512, bias2, 1, nullptr,0, nullptr,0, xbuf, 512, 16384, 512, 512);

  for(int i=0;i<6;i++){
    // self-attn (collapses to V + out-proj since seq_len == 1)
    ln_k<<<dim3(2048),dim3(256),0,stream>>>(tgt, 1024, ln1_s + i*512, ln1_b + i*512, H, 512);
    gemm(0,true, H,512,  sa_in_w + (size_t)i*1536*512 + (size_t)1024*512, 512,
         sa_in_b + i*1536 + 1024, 0, nullptr,0, nullptr,0, V,512, 8192,512,512);
    gemm(0,true, V,512,  sa_ow + (size_t)i*512*512, 512, sa_ob + i*512, 0,
         tgt,1024, nullptr,0, tgt,1024, 8192,512,512);
    // cross-attn (depends only on mem; ln2 dead)
    gemm(0,true, mem,1024, ca_in_w + (size_t)i*1536*512 + (size_t)1024*512, 512,
         ca_in_b + i*1536 + 1024, 0, nullptr,0, nullptr,0, V,512, 8192,512,512);
    gemm(0,true, V,512,  ca_ow + (size_t)i*512*512, 512, ca_ob + i*512, 0,
         tgt,1024, nullptr,0, tgt,1024, 8192,512,512);
    // FFN
    ln_k<<<dim3(2048),dim3(256),0,stream>>>(tgt, 1024, ln3_s + i*512, ln3_b + i*512, H, 512);
    gemm(1,true, H,512,  ff1_w + (size_t)i*2048*512, 512, ff1_b + i*2048, 0,
         nullptr,0, nullptr,0, F,2048, 8192,2048,512);
    gemm(0,true, F,2048, ff2_w + (size_t)i*512*2048, 2048, ff2_b + i*512, 0,
         tgt,1024, nullptr,0, tgt,1024, 8192,512,2048);
  }

  // shared head (plain bf16 ok post-routing-precision-wise)
  gemm(2,false, tgt,1024, se1_w,512,  se1_b,0, nullptr,0, nullptr,0, F,1024, 8192,1024,512);
  gemm(2,false, F,1024,   se2_w,1024, se2_b,0, nullptr,0, nullptr,0, V,512,  8192,512,1024);
  gemm(0,false, V,512,    se3_w,512,  se3_b,0, nullptr,0, nullptr,0, H,512,  8192,512,512);  // sh

  // router path (split precision: top-2 selection is discrete!)
  gemm(2,true,  tgt,1024, r1_w,512,   r1_b,0,  nullptr,0, nullptr,0, F2,256, 8192,256,512);
  router_k<<<dim3(2048),dim3(256),0,stream>>>(F2, r2_w, r2_b, gates);

  // out = sh @ po[:, :512].T + po_b
  gemm(0,false, H,512, po_w,4608, po_b,0, nullptr,0, nullptr,0, out,512, 8192,512,512);

  // experts (dense this round; gate scale folded into te3 epilogue)
  for(int e=0;e<8;e++){
    gemm(2,false, tgt,1024, te1_w + (size_t)e*1024*512, 512, te1_b + e*1024, 0,
         nullptr,0, nullptr,0, F,1024, 8192,1024,512);
    gemm(2,false, F,1024,   te2_w + (size_t)e*512*1024, 1024, te2_b + e*512, 0,
         nullptr,0, nullptr,0, V,512,  8192,512,1024);
    gemm(0,false, V,512,    te3_w + (size_t)e*512*512,  512,  te3_b + e*512, 0,
         nullptr,0, gates + e, 8, F2,512, 8192,512,512);   // EO = (..)*gate_e
    gemm(0,false, F2,512,   po_w + 512 + (size_t)e*512, 4608, nullptr,0,
         out,512, nullptr,0, out,512, 8192,512,512);       // out += EO @ po_e.T
  }
}

// Round 3
// 2822.411 us; speedup vs baseline: 1.8085x; 1.8085x over previous
//
#include <hip/hip_runtime.h>
#include <hip/hip_bf16.h>

typedef __attribute__((ext_vector_type(8))) short bf8_t;
typedef __attribute__((ext_vector_type(4))) float f4_t;

#define DEV static __device__ __forceinline__

DEV short f2bf(float x){
  unsigned u = __float_as_uint(x);
  u += 0x7fffu + ((u >> 16) & 1u);
  return (short)(u >> 16);
}
DEV float bf2f(short h){
  return __uint_as_float(((unsigned)(unsigned short)h) << 16);
}

// bijective XCD-chunked swizzle (m204)
DEV void swz(int& bx, int& by){
  int gx = gridDim.x, n = gx * gridDim.y;
  int lb = blockIdx.x + gx * blockIdx.y;
  int q = n >> 3, r = n & 7, xcd = lb & 7, idx = lb >> 3;
  int s = (xcd < r) ? (xcd * (q + 1) + idx) : (r * (q + 1) + (xcd - r) * q + idx);
  bx = s % gx; by = s / gx;
}

// ---------------- GEMM v2: bf16-plane inputs ----------------
// D = act(A @ W^T + bias) [*scale] [+res];  A,W as bf16 hi(/lo) planes.
// MODE 0: normal; 1: expert (W/bias selected by tile's expert via off[]); 2: + A-row gather via perm
template<int TM, int TN, bool SPLIT, int ACT, int MODE, int LB>
__global__ __launch_bounds__(256, LB)
void g2_k(const short* __restrict__ Ahi, const short* __restrict__ Alo, int lda,
          const short* __restrict__ Whi, const short* __restrict__ Wlo, int ldw, long wzs,
          const float* __restrict__ bias, long bzs,
          const float* __restrict__ res, int ldres,
          const float* __restrict__ scale,
          float* __restrict__ Df, int ldd,
          short* __restrict__ Dhi, short* __restrict__ Dlo, int lddp,
          const int* __restrict__ off, const int* __restrict__ perm, int K)
{
  constexpr int NS = SPLIT ? 2 : 1;
  constexpr int TM2 = TM / 2, TN2 = TN / 2, AM = TM / 32, AN = TN / 32;
  constexpr int AIT = TM / 64, BIT = TN / 64;
  __shared__ short As[NS][TM][40];   // 80B row stride: 16B-aligned, 2-way conflicts only (free)
  __shared__ short Bs[NS][TN][40];

  int bx, by; swz(bx, by);
  const int rowStart = by * TM, colStart = bx * TN;
  if constexpr (MODE >= 1) {
    if (rowStart >= off[8]) return;
    int e = 0;
    while (rowStart >= off[e + 1]) ++e;
    Whi += (long)e * wzs;
    if constexpr (SPLIT) Wlo += (long)e * wzs;
    bias += (long)e * bzs;
  }

  const int tid = threadIdx.x, lane = tid & 63, wid = tid >> 6;
  const int wr = wid >> 1, wc = wid & 1, fr = lane & 15, kg = lane >> 4;

  f4_t acc[AM][AN];
#pragma unroll
  for (int m = 0; m < AM; m++)
#pragma unroll
    for (int n = 0; n < AN; n++)
#pragma unroll
      for (int j = 0; j < 4; j++) acc[m][n][j] = 0.f;

  const short* pAh[AIT]; const short* pAl[AIT]; int aLr[AIT], aLc[AIT];
#pragma unroll
  for (int it = 0; it < AIT; it++) {
    int idx = tid + it * 256, r = idx >> 2, c8 = (idx & 3) << 3;
    aLr[it] = r; aLc[it] = c8;
    long rg = rowStart + r;
    if constexpr (MODE == 2) { int p = perm[rg]; rg = p < 0 ? 0 : p; }
    pAh[it] = Ahi + rg * (long)lda + c8;
    if constexpr (SPLIT) pAl[it] = Alo + rg * (long)lda + c8;
  }
  const short* pBh[BIT]; const short* pBl[BIT]; int bLr[BIT], bLc[BIT];
#pragma unroll
  for (int it = 0; it < BIT; it++) {
    int idx = tid + it * 256, r = idx >> 2, c8 = (idx & 3) << 3;
    bLr[it] = r; bLc[it] = c8;
    long rg = colStart + r;
    pBh[it] = Whi + rg * (long)ldw + c8;
    if constexpr (SPLIT) pBl[it] = Wlo + rg * (long)ldw + c8;
  }

  for (int kb = 0; kb < K; kb += 32) {
    bf8_t va[AIT], val[AIT], vb[BIT], vbl[BIT];
#pragma unroll
    for (int it = 0; it < AIT; it++) {
      va[it] = *(const bf8_t*)(pAh[it] + kb);
      if constexpr (SPLIT) val[it] = *(const bf8_t*)(pAl[it] + kb);
    }
#pragma unroll
    for (int it = 0; it < BIT; it++) {
      vb[it] = *(const bf8_t*)(pBh[it] + kb);
      if constexpr (SPLIT) vbl[it] = *(const bf8_t*)(pBl[it] + kb);
    }
    __syncthreads();
#pragma unroll
    for (int it = 0; it < AIT; it++) {
      *(bf8_t*)&As[0][aLr[it]][aLc[it]] = va[it];
      if constexpr (SPLIT) *(bf8_t*)&As[1][aLr[it]][aLc[it]] = val[it];
    }
#pragma unroll
    for (int it = 0; it < BIT; it++) {
      *(bf8_t*)&Bs[0][bLr[it]][bLc[it]] = vb[it];
      if constexpr (SPLIT) *(bf8_t*)&Bs[1][bLr[it]][bLc[it]] = vbl[it];
    }
    __syncthreads();

    bf8_t a0[AM], a1[AM], b0[AN], b1[AN];
#pragma unroll
    for (int m = 0; m < AM; m++) {
      a0[m] = *(const bf8_t*)&As[0][wr * TM2 + m * 16 + fr][kg * 8];
      if constexpr (SPLIT) a1[m] = *(const bf8_t*)&As[1][wr * TM2 + m * 16 + fr][kg * 8];
    }
#pragma unroll
    for (int n = 0; n < AN; n++) {
      b0[n] = *(const bf8_t*)&Bs[0][wc * TN2 + n * 16 + fr][kg * 8];
      if constexpr (SPLIT) b1[n] = *(const bf8_t*)&Bs[1][wc * TN2 + n * 16 + fr][kg * 8];
    }
#pragma unroll
    for (int m = 0; m < AM; m++)
#pragma unroll
      for (int n = 0; n < AN; n++) {
        acc[m][n] = __builtin_amdgcn_mfma_f32_16x16x32_bf16(a0[m], b0[n], acc[m][n], 0, 0, 0);
        if constexpr (SPLIT) {
          acc[m][n] = __builtin_amdgcn_mfma_f32_16x16x32_bf16(a0[m], b1[n], acc[m][n], 0, 0, 0);
          acc[m][n] = __builtin_amdgcn_mfma_f32_16x16x32_bf16(a1[m], b0[n], acc[m][n], 0, 0, 0);
        }
      }
  }

#pragma unroll
  for (int m = 0; m < AM; m++) {
#pragma unroll
    for (int n = 0; n < AN; n++) {
      const int col = colStart + wc * TN2 + n * 16 + fr;
#pragma unroll
      for (int j = 0; j < 4; j++) {
        const int row = rowStart + wr * TM2 + m * 16 + kg * 4 + j;
        float v = acc[m][n][j];
        if (bias) v += bias[col];
        if (ACT == 1) v = fmaxf(v, 0.f);
        if (ACT == 2) v = (v >= 0.f) ? v : 0.01f * v;
        if (scale) v *= scale[row];
        if (res) v += res[(size_t)row * ldres + col];
        if (Df) Df[(size_t)row * ldd + col] = v;
        if (Dhi) {
          short h = f2bf(v);
          Dhi[(size_t)row * lddp + col] = h;
          if (Dlo) Dlo[(size_t)row * lddp + col] = f2bf(v - bf2f(h));
        }
      }
    }
  }
}

// ---------------- GEMM v1: f32 inputs, in-staging conversion ----------------
// DEMUX: even rows -> Df f32 (row/2), odd rows -> Dhi/Dlo planes (row/2)
template<bool SPLIT, bool DEMUX>
__global__ __launch_bounds__(256, 2)
void g1_k(const float* __restrict__ A, int lda, long zsA,
          const float* __restrict__ W, int ldw, long zsB,
          const float* __restrict__ bias, int posbias,
          float* __restrict__ Df, short* __restrict__ Dhi, short* __restrict__ Dlo,
          int ldd, long zsD, int K)
{
  constexpr int NS = SPLIT ? 2 : 1;
  __shared__ short As[NS][128][40];
  __shared__ short Bs[NS][128][40];
  const long z = blockIdx.z;
  A += z * zsA; W += z * zsB;
  if (Df)  Df  += z * zsD;
  if (Dhi) Dhi += z * zsD;

  int bx, by; swz(bx, by);
  const int tid = threadIdx.x, lane = tid & 63, wid = tid >> 6;
  const int wr = wid >> 1, wc = wid & 1, fr = lane & 15, kg = lane >> 4;

  f4_t acc[4][4];
#pragma unroll
  for (int m = 0; m < 4; m++)
#pragma unroll
    for (int n = 0; n < 4; n++)
#pragma unroll
      for (int j = 0; j < 4; j++) acc[m][n][j] = 0.f;

  const int srow = tid >> 1, skoff = (tid & 1) << 4;
  const float* pA = A + (size_t)((size_t)by * 128 + srow) * lda + skoff;
  const float* pW = W + (size_t)((size_t)bx * 128 + srow) * ldw + skoff;

  for (int kb = 0; kb < K; kb += 32) {
    float va[16], vw[16];
    {
      const f4_t* a4 = (const f4_t*)(pA + kb);
      const f4_t* w4 = (const f4_t*)(pW + kb);
#pragma unroll
      for (int q = 0; q < 4; q++) {
        f4_t ta = a4[q], tw = w4[q];
#pragma unroll
        for (int j = 0; j < 4; j++) { va[q * 4 + j] = ta[j]; vw[q * 4 + j] = tw[j]; }
      }
    }
    __syncthreads();
#pragma unroll
    for (int h = 0; h < 2; h++) {
      bf8_t ha, hw;
#pragma unroll
      for (int j = 0; j < 8; j++) { ha[j] = f2bf(va[h * 8 + j]); hw[j] = f2bf(vw[h * 8 + j]); }
      *(bf8_t*)&As[0][srow][skoff + h * 8] = ha;
      *(bf8_t*)&Bs[0][srow][skoff + h * 8] = hw;
      if constexpr (SPLIT) {
        bf8_t la, lw;
#pragma unroll
        for (int j = 0; j < 8; j++) {
          la[j] = f2bf(va[h * 8 + j] - bf2f(ha[j]));
          lw[j] = f2bf(vw[h * 8 + j] - bf2f(hw[j]));
        }
        *(bf8_t*)&As[NS - 1][srow][skoff + h * 8] = la;
        *(bf8_t*)&Bs[NS - 1][srow][skoff + h * 8] = lw;
      }
    }
    __syncthreads();

    bf8_t a0[4], b0[4], a1[4], b1[4];
#pragma unroll
    for (int m = 0; m < 4; m++) {
      a0[m] = *(const bf8_t*)&As[0][wr * 64 + m * 16 + fr][kg * 8];
      if constexpr (SPLIT) a1[m] = *(const bf8_t*)&As[NS - 1][wr * 64 + m * 16 + fr][kg * 8];
    }
#pragma unroll
    for (int n = 0; n < 4; n++) {
      b0[n] = *(const bf8_t*)&Bs[0][wc * 64 + n * 16 + fr][kg * 8];
      if constexpr (SPLIT) b1[n] = *(const bf8_t*)&Bs[NS - 1][wc * 64 + n * 16 + fr][kg * 8];
    }
#pragma unroll
    for (int m = 0; m < 4; m++)
#pragma unroll
      for (int n = 0; n < 4; n++) {
        acc[m][n] = __builtin_amdgcn_mfma_f32_16x16x32_bf16(a0[m], b0[n], acc[m][n], 0, 0, 0);
        if constexpr (SPLIT) {
          acc[m][n] = __builtin_amdgcn_mfma_f32_16x16x32_bf16(a0[m], b1[n], acc[m][n], 0, 0, 0);
          acc[m][n] = __builtin_amdgcn_mfma_f32_16x16x32_bf16(a1[m], b0[n], acc[m][n], 0, 0, 0);
        }
      }
  }

  const int Ncols = (int)gridDim.x * 128;
#pragma unroll
  for (int m = 0; m < 4; m++) {
#pragma unroll
    for (int n = 0; n < 4; n++) {
      const int col = bx * 128 + wc * 64 + n * 16 + fr;
#pragma unroll
      for (int j = 0; j < 4; j++) {
        const int row = by * 128 + wr * 64 + m * 16 + kg * 4 + j;
        float v = acc[m][n][j];
        if (bias) v += bias[posbias ? ((row & 1) * Ncols + col) : col];
        if constexpr (DEMUX) {
          const size_t o = (size_t)(row >> 1) * ldd + col;
          if (row & 1) { short h = f2bf(v); Dhi[o] = h; Dlo[o] = f2bf(v - bf2f(h)); }
          else Df[o] = v;
        } else {
          if (Dhi) Dhi[(size_t)row * ldd + col] = f2bf(v);
          else     Df[(size_t)row * ldd + col] = v;
        }
      }
    }
  }
}

// ---------------- LayerNorm(512) -> bf16 hi/lo planes ----------------
__global__ __launch_bounds__(256)
void ln2_k(const float* __restrict__ x, int ldx,
           const float* __restrict__ s, const float* __restrict__ b,
           short* __restrict__ hi, short* __restrict__ lo, int ldy)
{
  const int lane = threadIdx.x & 63;
  const int row = blockIdx.x * 4 + (threadIdx.x >> 6);
  const float* xr = x + (size_t)row * ldx + lane * 8;
  f4_t v0 = *(const f4_t*)xr;
  f4_t v1 = *(const f4_t*)(xr + 4);
  float sum = (v0[0] + v0[1]) + (v0[2] + v0[3]) + ((v1[0] + v1[1]) + (v1[2] + v1[3]));
#pragma unroll
  for (int o = 32; o; o >>= 1) sum += __shfl_xor(sum, o, 64);
  const float mean = sum * (1.f / 512.f);
  float vs = 0.f;
#pragma unroll
  for (int j = 0; j < 4; j++) { float d0 = v0[j] - mean, d1 = v1[j] - mean; vs += d0 * d0 + d1 * d1; }
#pragma unroll
  for (int o = 32; o; o >>= 1) vs += __shfl_xor(vs, o, 64);
  const float rstd = rsqrtf(vs * (1.f / 512.f) + 1e-5f);
  const float* sp = s + lane * 8; const float* bp = b + lane * 8;
  bf8_t h, l;
#pragma unroll
  for (int j = 0; j < 4; j++) {
    float y0 = (v0[j] - mean) * rstd * sp[j] + bp[j];
    float y1 = (v1[j] - mean) * rstd * sp[j + 4] + bp[j + 4];
    short h0 = f2bf(y0); h[j] = h0;     l[j] = f2bf(y0 - bf2f(h0));
    short h1 = f2bf(y1); h[j + 4] = h1; l[j + 4] = f2bf(y1 - bf2f(h1));
  }
  *(bf8_t*)&hi[(size_t)row * ldy + lane * 8] = h;
  *(bf8_t*)&lo[(size_t)row * ldy + lane * 8] = l;
}

// ---------------- f32 -> bf16 hi(/lo) planes ----------------
__global__ __launch_bounds__(256)
void conv_k(const float* __restrict__ src, long zs, int ld, int cols,
            short* __restrict__ hi, short* __restrict__ lo, long dzs)
{
  const long z = blockIdx.z;
  int idx = blockIdx.x * 256 + threadIdx.x;
  int cpr = cols >> 3;
  int row = idx / cpr, c8 = (idx % cpr) << 3;
  const float* p = src + z * zs + (size_t)row * ld + c8;
  f4_t v0 = *(const f4_t*)p, v1 = *(const f4_t*)(p + 4);
  bf8_t h, l;
#pragma unroll
  for (int j = 0; j < 4; j++) {
    short h0 = f2bf(v0[j]); h[j] = h0;     l[j] = f2bf(v0[j] - bf2f(h0));
    short h1 = f2bf(v1[j]); h[j + 4] = h1; l[j + 4] = f2bf(v1[j] - bf2f(h1));
  }
  size_t dof = (size_t)z * dzs + (size_t)row * cols + c8;
  *(bf8_t*)&hi[dof] = h;
  if (lo) *(bf8_t*)&lo[dof] = l;
}

// ---------------- te3 transpose: (8,512o,512g) -> (8,512g,512o) ----------------
__global__ __launch_bounds__(256)
void tr_k(const float* __restrict__ in, float* __restrict__ out)
{
  __shared__ float t[32][33];
  const int e = blockIdx.z, ob = blockIdx.x * 32, gb = blockIdx.y * 32;
  const int tx = threadIdx.x & 31, ty = threadIdx.x >> 5;
  const float* I = in + ((size_t)e * 512 + ob) * 512 + gb;
  float* O = out + ((size_t)e * 512 + gb) * 512 + ob;
#pragma unroll
  for (int i = 0; i < 4; i++) t[ty + 8 * i][tx] = I[(size_t)(ty + 8 * i) * 512 + tx];
  __syncthreads();
#pragma unroll
  for (int i = 0; i < 4; i++) O[(size_t)(ty + 8 * i) * 512 + tx] = t[tx][ty + 8 * i];
}

// ---------------- bc[e][oo] = sum_o po_w[oo][512+512e+o] * te3_b[e][o] ----------------
__global__ __launch_bounds__(256)
void bc_k(const float* __restrict__ po, const float* __restrict__ te3b, float* __restrict__ bc)
{
  int idx = blockIdx.x * 256 + threadIdx.x;   // 4096
  int e = idx >> 9, oo = idx & 511;
  const float* p = po + (size_t)oo * 4608 + 512 + (size_t)e * 512;
  const float* tb = te3b + (size_t)e * 512;
  float s = 0.f;
#pragma unroll 4
  for (int g = 0; g < 512; g += 4) {
    f4_t a = *(const f4_t*)(p + g);
    f4_t b = *(const f4_t*)(tb + g);
    s += a[0] * b[0] + a[1] * b[1] + a[2] * b[2] + a[3] * b[3];
  }
  bc[idx] = s;
}

// ---------------- router helpers ----------------
__global__ __launch_bounds__(256)
void init_k(int* __restrict__ cnt, int* __restrict__ perm, float* __restrict__ pgate)
{
  int i = blockIdx.x * 256 + threadIdx.x;
  if (i < 16) cnt[i] = 0;
  if (i < 17408) { perm[i] = -1; pgate[i] = 0.f; }
}

__global__ __launch_bounds__(256)
void router_k(const float* __restrict__ R1, const float* __restrict__ r2w,
              const float* __restrict__ r2b, int2* __restrict__ ridx,
              float2* __restrict__ rgv, int* __restrict__ cnt)
{
  const int lane = threadIdx.x & 63;
  const int row = blockIdx.x * 4 + (threadIdx.x >> 6);
  f4_t xv = *(const f4_t*)(R1 + (size_t)row * 256 + lane * 4);
  float lg[8];
#pragma unroll
  for (int e = 0; e < 8; e++) {
    f4_t wv = *(const f4_t*)(r2w + e * 256 + lane * 4);
    float p = xv[0] * wv[0] + xv[1] * wv[1] + xv[2] * wv[2] + xv[3] * wv[3];
#pragma unroll
    for (int o = 32; o; o >>= 1) p += __shfl_xor(p, o, 64);
    lg[e] = p + r2b[e];
  }
  int i1 = 0; float v1 = lg[0];
#pragma unroll
  for (int e = 1; e < 8; e++) if (lg[e] > v1) { v1 = lg[e]; i1 = e; }
  int i2 = -1; float v2 = -3.4e38f;
#pragma unroll
  for (int e = 0; e < 8; e++) if (e != i1 && lg[e] > v2) { v2 = lg[e]; i2 = e; }
  const float p2 = 1.f / (1.f + expf(v1 - v2));
  const float p1 = 1.f - p2;
  if (lane == 0) {
    ridx[row] = make_int2(i1, i2);
    rgv[row] = make_float2(p1, p2);
    atomicAdd(&cnt[i1], 1); atomicAdd(&cnt[i2], 1);
  }
}

__global__ void offs_k(const int* __restrict__ cnt, int* __restrict__ off)
{
  if (threadIdx.x == 0) {
    int a = 0; off[0] = 0;
    for (int e = 0; e < 8; e++) { a += (cnt[e] + 127) & ~127; off[e + 1] = a; }
  }
}

__global__ __launch_bounds__(256)
void scat_k(const int2* __restrict__ ridx, const float2* __restrict__ rgv,
            const int* __restrict__ off, int* __restrict__ fill,
            int* __restrict__ perm, float* __restrict__ pgate, int2* __restrict__ islot)
{
  int r = blockIdx.x * 256 + threadIdx.x;
  int2 ii = ridx[r]; float2 gg = rgv[r];
  int p0 = off[ii.x] + atomicAdd(&fill[ii.x], 1); perm[p0] = r; pgate[p0] = gg.x;
  int p1 = off[ii.y] + atomicAdd(&fill[ii.y], 1); perm[p1] = r; pgate[p1] = gg.y;
  islot[r] = make_int2(p0, p1);
}

__global__ __launch_bounds__(256)
void fadd_k(const int2* __restrict__ islot, const float* __restrict__ EO, float* __restrict__ out)
{
  int idx = blockIdx.x * 256 + threadIdx.x;
  int r = idx >> 7, c4 = (idx & 127) << 2;
  int2 s = islot[r];
  f4_t a = *(const f4_t*)&EO[(size_t)s.x * 512 + c4];
  f4_t b = *(const f4_t*)&EO[(size_t)s.y * 512 + c4];
  float* op = &out[(size_t)r * 512 + c4];
  f4_t o = *(const f4_t*)op;
#pragma unroll
  for (int j = 0; j < 4; j++) o[j] += a[j] + b[j];
  *(f4_t*)op = o;
}

__global__ void bias2_k(const float* __restrict__ pib, const float* __restrict__ pos,
                        float* __restrict__ bias2)
{
  int i = blockIdx.x * 256 + threadIdx.x;
  if (i < 1024) bias2[i] = pib[i & 511] + pos[i];
}

// =====================================================================

extern "C" void kernel_launch(void* const* d_in, const int* in_sizes, int n_in,
                              void* d_out, int out_size, void* d_ws, size_t ws_size,
                              hipStream_t stream)
{
  (void)in_sizes; (void)n_in; (void)out_size; (void)ws_size;
  const float* src     = (const float*)d_in[0];
  const float* piw     = (const float*)d_in[1];
  const float* pib     = (const float*)d_in[2];
  const float* pos     = (const float*)d_in[3];
  const float* ln1_s   = (const float*)d_in[4];
  const float* ln1_b   = (const float*)d_in[5];
  // ln2 (d_in[6],[7]) dead: feeds only Q; softmax over 1 key == 1
  const float* ln3_s   = (const float*)d_in[8];
  const float* ln3_b   = (const float*)d_in[9];
  const float* sa_in_w = (const float*)d_in[10];
  const float* sa_in_b = (const float*)d_in[11];
  const float* sa_ow   = (const float*)d_in[12];
  const float* sa_ob   = (const float*)d_in[13];
  const float* ca_in_w = (const float*)d_in[14];
  const float* ca_in_b = (const float*)d_in[15];
  const float* ca_ow   = (const float*)d_in[16];
  const float* ca_ob   = (const float*)d_in[17];
  const float* ff1_w   = (const float*)d_in[18];
  const float* ff1_b   = (const float*)d_in[19];
  const float* ff2_w   = (const float*)d_in[20];
  const float* ff2_b   = (const float*)d_in[21];
  const float* r1_w    = (const float*)d_in[22];
  const float* r1_b    = (const float*)d_in[23];
  const float* r2_w    = (const float*)d_in[24];
  const float* r2_b    = (const float*)d_in[25];
  const float* se1_w   = (const float*)d_in[26];
  const float* se1_b   = (const float*)d_in[27];
  const float* se2_w   = (const float*)d_in[28];
  const float* se2_b   = (const float*)d_in[29];
  const float* se3_w   = (const float*)d_in[30];
  const float* se3_b   = (const float*)d_in[31];
  const float* te1_w   = (const float*)d_in[32];
  const float* te1_b   = (const float*)d_in[33];
  const float* te2_w   = (const float*)d_in[34];
  const float* te2_b   = (const float*)d_in[35];
  const float* te3_w   = (const float*)d_in[36];
  const float* te3_b   = (const float*)d_in[37];
  const float* po_w    = (const float*)d_in[38];
  const float* po_b    = (const float*)d_in[39];
  float* out = (float*)d_out;

  // ------------- arena (total ~134.1 MB <= proven 134.48 MB) -------------
  const size_t MiB = 1048576;
  char* base = (char*)d_ws;
  // loop phase
  float* tgt   = (float*)(base + 0 * MiB);    // 8192x512 f32, ld 512
  short* MemHi = (short*)(base + 16 * MiB);
  short* MemLo = (short*)(base + 24 * MiB);
  short* Hhi   = (short*)(base + 32 * MiB);
  short* Hlo   = (short*)(base + 40 * MiB);
  short* Fhi   = (short*)(base + 48 * MiB);   // 8192x2048
  short* Flo   = (short*)(base + 80 * MiB);
  short* Vhi   = (short*)(base + 48 * MiB);   // alias F (attn vs FFN disjoint)
  short* Vlo   = (short*)(base + 56 * MiB);
  // per-layer weight scratch [112,124)
  short* wsV   = (short*)(base + 112 * MiB);  // 8 planes of 512x512
  short* saVhi = wsV;             short* saVlo = wsV + 262144;
  short* saOhi = wsV + 524288;    short* saOlo = wsV + 786432;
  short* caVhi = wsV + 1048576;   short* caVlo = wsV + 1310720;
  short* caOhi = wsV + 1572864;   short* caOlo = wsV + 1835008;
  short* ff1hi = (short*)(base + 116 * MiB);  short* ff1lo = ff1hi + 1048576;
  short* ff2hi = (short*)(base + 120 * MiB);  short* ff2lo = ff2hi + 1048576;
  // head phase (aliases of dead loop regions)
  short* tgtHi = Hhi;  short* tgtLo = Hlo;            // written by last ff2
  float* te3T  = (float*)(base + 0 * MiB);            // 8 MiB, before S1
  short* S1hi  = (short*)(base + 0 * MiB);            // 8192x1024
  short* S2hi  = (short*)(base + 16 * MiB);
  short* SHhi  = (short*)(base + 24 * MiB);
  short* X1hi  = (short*)(base + 48 * MiB);           // 17408x1024 -> [48,82)
  short* X2hi  = (short*)(base + 82 * MiB);           // 17408x512  -> [82,99)
  float* EO    = (float*)(base + 48 * MiB);           // over dead X1
  float* F2    = (float*)(base + 104 * MiB);          // 8192x256 f32
  short* te1hi = (short*)(base + 104 * MiB);          // after router (F2 dead)
  short* te2hi = (short*)(base + 112 * MiB);          // over layer scratch
  short* Wchi  = (short*)(base + 120 * MiB);
  // persistent small region @124MiB
  char*  ps    = base + 124 * MiB;
  size_t cur = 0;
  auto alloc = [&](size_t bytes) { char* r = ps + cur; cur = (cur + bytes + 255) & ~(size_t)255; return r; };
  float*  bias2 = (float*)alloc(1024 * 4);
  float*  bc    = (float*)alloc(4096 * 4);
  int*    cnt   = (int*)  alloc(64 * 4);   // cnt[8], fill[8], off[9]
  int*    fill  = cnt + 8;
  int*    offs  = cnt + 16;
  int2*   ridx  = (int2*) alloc(8192 * 8);
  float2* rgv   = (float2*)alloc(8192 * 8);
  int2*   islot = (int2*) alloc(8192 * 8);
  int*    perm  = (int*)  alloc(17408 * 4);
  float*  pgate = (float*)alloc(17408 * 4);
  short*  r1hi  = (short*)alloc(524288);  short* r1lo = r1hi + 131072;
  short*  se1hi = (short*)alloc(1048576);
  short*  se2hi = (short*)alloc(1048576);
  short*  se3hi = (short*)alloc(524288);
  short*  pomhi = (short*)alloc(524288);

  auto conv = [&](const float* s_, long zs, int ld, int rows, int cols, int z,
                  short* hi, short* lo, long dzs) {
    conv_k<<<dim3(rows * cols / 2048, 1, z), dim3(256), 0, stream>>>(s_, zs, ld, cols, hi, lo, dzs);
  };

  // ---------------- pre-phase ----------------
  bias2_k<<<dim3(4), dim3(256), 0, stream>>>(pib, pos, bias2);
  conv(r1_w, 0, 512, 256, 512, 1, r1hi, r1lo, 0);
  conv(se1_w, 0, 512, 1024, 512, 1, se1hi, nullptr, 0);
  conv(se2_w, 0, 1024, 512, 1024, 1, se2hi, nullptr, 0);
  conv(se3_w, 0, 512, 512, 512, 1, se3hi, nullptr, 0);
  conv(po_w, 0, 4608, 512, 512, 1, pomhi, nullptr, 0);
  bc_k<<<dim3(16), dim3(256), 0, stream>>>(po_w, te3_b, bc);

  // input proj: even rows -> tgt f32, odd rows -> Mem planes (DEMUX)
  g1_k<true, true><<<dim3(4, 128, 1), dim3(256), 0, stream>>>(
      src, 512, 0, piw, 512, 0, bias2, 1, tgt, MemHi, MemLo, 512, 0, 512);

  // ---------------- trunk loop ----------------
  for (int i = 0; i < 6; i++) {
    conv(sa_in_w + (size_t)i * 786432 + 524288, 0, 512, 512, 512, 1, saVhi, saVlo, 0);
    conv(sa_ow + (size_t)i * 262144, 0, 512, 512, 512, 1, saOhi, saOlo, 0);
    conv(ca_in_w + (size_t)i * 786432 + 524288, 0, 512, 512, 512, 1, caVhi, caVlo, 0);
    conv(ca_ow + (size_t)i * 262144, 0, 512, 512, 512, 1, caOhi, caOlo, 0);
    conv(ff1_w + (size_t)i * 1048576, 0, 512, 2048, 512, 1, ff1hi, ff1lo, 0);
    conv(ff2_w + (size_t)i * 1048576, 0, 2048, 512, 2048, 1, ff2hi, ff2lo, 0);

    ln2_k<<<dim3(2048), dim3(256), 0, stream>>>(tgt, 512, ln1_s + i * 512, ln1_b + i * 512, Hhi, Hlo, 512);
    g2_k<64, 128, true, 0, 0, 2><<<dim3(4, 128), 256, 0, stream>>>(
        Hhi, Hlo, 512, saVhi, saVlo, 512, 0, sa_in_b + i * 1536 + 1024, 0,
        nullptr, 0, nullptr, nullptr, 0, Vhi, Vlo, 512, nullptr, nullptr, 512);
    g2_k<64, 128, true, 0, 0, 2><<<dim3(4, 128), 256, 0, stream>>>(
        Vhi, Vlo, 512, saOhi, saOlo, 512, 0, sa_ob + i * 512, 0,
        tgt, 512, nullptr, tgt, 512, nullptr, nullptr, 0, nullptr, nullptr, 512);
    g2_k<64, 128, true, 0, 0, 2><<<dim3(4, 128), 256, 0, stream>>>(
        MemHi, MemLo, 512, caVhi, caVlo, 512, 0, ca_in_b + i * 1536 + 1024, 0,
        nullptr, 0, nullptr, nullptr, 0, Vhi, Vlo, 512, nullptr, nullptr, 512);
    g2_k<64, 128, true, 0, 0, 2><<<dim3(4, 128), 256, 0, stream>>>(
        Vhi, Vlo, 512, caOhi, caOlo, 512, 0, ca_ob + i * 512, 0,
        tgt, 512, nullptr, tgt, 512, nullptr, nullptr, 0, nullptr, nullptr, 512);
    ln2_k<<<dim3(2048), dim3(256), 0, stream>>>(tgt, 512, ln3_s + i * 512, ln3_b + i * 512, Hhi, Hlo, 512);
    g2_k<128, 128, true, 1, 0, 2><<<dim3(16, 64), 256, 0, stream>>>(
        Hhi, Hlo, 512, ff1hi, ff1lo, 512, 0, ff1_b + i * 2048, 0,
        nullptr, 0, nullptr, nullptr, 0, Fhi, Flo, 2048, nullptr, nullptr, 512);
    bool last = (i == 5);
    g2_k<64, 128, true, 0, 0, 2><<<dim3(4, 128), 256, 0, stream>>>(
        Fhi, Flo, 2048, ff2hi, ff2lo, 2048, 0, ff2_b + i * 512, 0,
        tgt, 512, nullptr, tgt, 512,
        last ? tgtHi : nullptr, last ? tgtLo : nullptr, 512, nullptr, nullptr, 2048);
  }

  // ---------------- router ----------------
  init_k<<<dim3(68), dim3(256), 0, stream>>>(cnt, perm, pgate);
  g2_k<64, 128, true, 2, 0, 2><<<dim3(2, 128), 256, 0, stream>>>(
      tgtHi, tgtLo, 512, r1hi, r1lo, 512, 0, r1_b, 0,
      nullptr, 0, nullptr, F2, 256, nullptr, nullptr, 0, nullptr, nullptr, 512);
  router_k<<<dim3(2048), dim3(256), 0, stream>>>(F2, r2_w, r2_b, ridx, rgv, cnt);
  offs_k<<<dim3(1), dim3(64), 0, stream>>>(cnt, offs);
  scat_k<<<dim3(32), dim3(256), 0, stream>>>(ridx, rgv, offs, fill, perm, pgate, islot);

  // ---------------- fused te3*po precompute (Wc) + expert-weight planes ----------------
  tr_k<<<dim3(16, 16, 8), dim3(256), 0, stream>>>(te3_w, te3T);
  g1_k<false, false><<<dim3(4, 4, 8), dim3(256), 0, stream>>>(
      po_w + 512, 4608, 512, te3T, 512, 262144,
      nullptr, 0, nullptr, Wchi, nullptr, 512, 262144, 512);
  conv(te1_w, 524288, 512, 1024, 512, 8, te1hi, nullptr, 524288);   // over dead F2
  conv(te2_w, 524288, 1024, 512, 1024, 8, te2hi, nullptr, 524288);  // over dead layer scratch

  // ---------------- shared head ----------------
  g2_k<128, 128, false, 2, 0, 3><<<dim3(8, 64), 256, 0, stream>>>(
      tgtHi, nullptr, 512, se1hi, nullptr, 512, 0, se1_b, 0,
      nullptr, 0, nullptr, nullptr, 0, S1hi, nullptr, 1024, nullptr, nullptr, 512);
  g2_k<64, 128, false, 2, 0, 4><<<dim3(4, 128), 256, 0, stream>>>(
      S1hi, nullptr, 1024, se2hi, nullptr, 1024, 0, se2_b, 0,
      nullptr, 0, nullptr, nullptr, 0, S2hi, nullptr, 512, nullptr, nullptr, 1024);
  g2_k<64, 128, false, 0, 0, 4><<<dim3(4, 128), 256, 0, stream>>>(
      S2hi, nullptr, 512, se3hi, nullptr, 512, 0, se3_b, 0,
      nullptr, 0, nullptr, nullptr, 0, SHhi, nullptr, 512, nullptr, nullptr, 512);
  g2_k<64, 128, false, 0, 0, 4><<<dim3(4, 128), 256, 0, stream>>>(
      SHhi, nullptr, 512, pomhi, nullptr, 512, 0, po_b, 0,
      nullptr, 0, nullptr, out, 512, nullptr, nullptr, 0, nullptr, nullptr, 512);

  // ---------------- sparse experts (top-2) ----------------
  g2_k<128, 128, false, 2, 2, 3><<<dim3(8, 136), 256, 0, stream>>>(
      tgtHi, nullptr, 512, te1hi, nullptr, 512, 524288, te1_b, 1024,
      nullptr, 0, nullptr, nullptr, 0, X1hi, nullptr, 1024, offs, perm, 512);
  g2_k<64, 128, false, 2, 1, 4><<<dim3(4, 272), 256, 0, stream>>>(
      X1hi, nullptr, 1024, te2hi, nullptr, 1024, 524288, te2_b, 512,
      nullptr, 0, nullptr, nullptr, 0, X2hi, nullptr, 512, offs, nullptr, 1024);
  g2_k<64, 128, false, 0, 1, 4><<<dim3(4, 272), 256, 0, stream>>>(
      X2hi, nullptr, 512, Wchi, nullptr, 512, 262144, bc, 512,
      nullptr, 0, pgate, EO, 512, nullptr, nullptr, 0, offs, nullptr, 512);
  fadd_k<<<dim3(4096), dim3(256), 0, stream>>>(islot, EO, out);
}

// Round 5
// 2512.579 us; speedup vs baseline: 2.0316x; 1.1233x over previous
//
#include <hip/hip_runtime.h>
#include <hip/hip_bf16.h>

typedef __attribute__((ext_vector_type(8))) short bf8_t;
typedef __attribute__((ext_vector_type(4))) float f4_t;

#define DEV static __device__ __forceinline__

DEV short f2bf(float x){
  unsigned u = __float_as_uint(x);
  u += 0x7fffu + ((u >> 16) & 1u);
  return (short)(u >> 16);
}
DEV float bf2f(short h){
  return __uint_as_float(((unsigned)(unsigned short)h) << 16);
}

// bijective XCD-chunked swizzle (m204)
DEV void swz(int& bx, int& by){
  int gx = gridDim.x, n = gx * gridDim.y;
  int lb = blockIdx.x + gx * blockIdx.y;
  int q = n >> 3, r = n & 7, xcd = lb & 7, idx = lb >> 3;
  int s = (xcd < r) ? (xcd * (q + 1) + idx) : (r * (q + 1) + (xcd - r) * q + idx);
  bx = s % gx; by = s / gx;
}

// ---------------- GEMM v2: bf16-plane inputs ----------------
// D = act(A @ W^T + bias) [*scale] [+res];  A,W as bf16 hi(/lo) planes.
// MODE 0: normal; 1: expert (W/bias selected by tile's expert via off[]); 2: + A-row gather via perm
template<int TM, int TN, bool SPLIT, int ACT, int MODE, int LB>
__global__ __launch_bounds__(256, LB)
void g2_k(const short* __restrict__ Ahi, const short* __restrict__ Alo, int lda,
          const short* __restrict__ Whi, const short* __restrict__ Wlo, int ldw, long wzs,
          const float* __restrict__ bias, long bzs,
          const float* __restrict__ res, int ldres,
          const float* __restrict__ scale,
          float* __restrict__ Df, int ldd,
          short* __restrict__ Dhi, short* __restrict__ Dlo, int lddp,
          const int* __restrict__ off, const int* __restrict__ perm, int K)
{
  constexpr int NS = SPLIT ? 2 : 1;
  constexpr int TM2 = TM / 2, TN2 = TN / 2, AM = TM / 32, AN = TN / 32;
  constexpr int AIT = TM / 64, BIT = TN / 64;
  __shared__ short As[NS][TM][40];   // 80B row stride: 16B-aligned, 2-way conflicts only (free)
  __shared__ short Bs[NS][TN][40];

  int bx, by; swz(bx, by);
  const int rowStart = by * TM, colStart = bx * TN;
  if constexpr (MODE >= 1) {
    if (rowStart >= off[8]) return;
    int e = 0;
    while (rowStart >= off[e + 1]) ++e;
    Whi += (long)e * wzs;
    if constexpr (SPLIT) Wlo += (long)e * wzs;
    bias += (long)e * bzs;
  }

  const int tid = threadIdx.x, lane = tid & 63, wid = tid >> 6;
  const int wr = wid >> 1, wc = wid & 1, fr = lane & 15, kg = lane >> 4;

  f4_t acc[AM][AN];
#pragma unroll
  for (int m = 0; m < AM; m++)
#pragma unroll
    for (int n = 0; n < AN; n++)
#pragma unroll
      for (int j = 0; j < 4; j++) acc[m][n][j] = 0.f;

  const short* pAh[AIT]; const short* pAl[AIT]; int aLr[AIT], aLc[AIT];
#pragma unroll
  for (int it = 0; it < AIT; it++) {
    int idx = tid + it * 256, r = idx >> 2, c8 = (idx & 3) << 3;
    aLr[it] = r; aLc[it] = c8;
    long rg = rowStart + r;
    if constexpr (MODE == 2) { int p = perm[rg]; rg = p < 0 ? 0 : p; }
    pAh[it] = Ahi + rg * (long)lda + c8;
    if constexpr (SPLIT) pAl[it] = Alo + rg * (long)lda + c8;
  }
  const short* pBh[BIT]; const short* pBl[BIT]; int bLr[BIT], bLc[BIT];
#pragma unroll
  for (int it = 0; it < BIT; it++) {
    int idx = tid + it * 256, r = idx >> 2, c8 = (idx & 3) << 3;
    bLr[it] = r; bLc[it] = c8;
    long rg = colStart + r;
    pBh[it] = Whi + rg * (long)ldw + c8;
    if constexpr (SPLIT) pBl[it] = Wlo + rg * (long)ldw + c8;
  }

  for (int kb = 0; kb < K; kb += 32) {
    bf8_t va[AIT], val[AIT], vb[BIT], vbl[BIT];
#pragma unroll
    for (int it = 0; it < AIT; it++) {
      va[it] = *(const bf8_t*)(pAh[it] + kb);
      if constexpr (SPLIT) val[it] = *(const bf8_t*)(pAl[it] + kb);
    }
#pragma unroll
    for (int it = 0; it < BIT; it++) {
      vb[it] = *(const bf8_t*)(pBh[it] + kb);
      if constexpr (SPLIT) vbl[it] = *(const bf8_t*)(pBl[it] + kb);
    }
    __syncthreads();
#pragma unroll
    for (int it = 0; it < AIT; it++) {
      *(bf8_t*)&As[0][aLr[it]][aLc[it]] = va[it];
      if constexpr (SPLIT) *(bf8_t*)&As[1][aLr[it]][aLc[it]] = val[it];
    }
#pragma unroll
    for (int it = 0; it < BIT; it++) {
      *(bf8_t*)&Bs[0][bLr[it]][bLc[it]] = vb[it];
      if constexpr (SPLIT) *(bf8_t*)&Bs[1][bLr[it]][bLc[it]] = vbl[it];
    }
    __syncthreads();

    bf8_t a0[AM], a1[AM], b0[AN], b1[AN];
#pragma unroll
    for (int m = 0; m < AM; m++) {
      a0[m] = *(const bf8_t*)&As[0][wr * TM2 + m * 16 + fr][kg * 8];
      if constexpr (SPLIT) a1[m] = *(const bf8_t*)&As[1][wr * TM2 + m * 16 + fr][kg * 8];
    }
#pragma unroll
    for (int n = 0; n < AN; n++) {
      b0[n] = *(const bf8_t*)&Bs[0][wc * TN2 + n * 16 + fr][kg * 8];
      if constexpr (SPLIT) b1[n] = *(const bf8_t*)&Bs[1][wc * TN2 + n * 16 + fr][kg * 8];
    }
#pragma unroll
    for (int m = 0; m < AM; m++)
#pragma unroll
      for (int n = 0; n < AN; n++) {
        acc[m][n] = __builtin_amdgcn_mfma_f32_16x16x32_bf16(a0[m], b0[n], acc[m][n], 0, 0, 0);
        if constexpr (SPLIT) {
          acc[m][n] = __builtin_amdgcn_mfma_f32_16x16x32_bf16(a0[m], b1[n], acc[m][n], 0, 0, 0);
          acc[m][n] = __builtin_amdgcn_mfma_f32_16x16x32_bf16(a1[m], b0[n], acc[m][n], 0, 0, 0);
        }
      }
  }

#pragma unroll
  for (int m = 0; m < AM; m++) {
#pragma unroll
    for (int n = 0; n < AN; n++) {
      const int col = colStart + wc * TN2 + n * 16 + fr;
#pragma unroll
      for (int j = 0; j < 4; j++) {
        const int row = rowStart + wr * TM2 + m * 16 + kg * 4 + j;
        float v = acc[m][n][j];
        if (bias) v += bias[col];
        if (ACT == 1) v = fmaxf(v, 0.f);
        if (ACT == 2) v = (v >= 0.f) ? v : 0.01f * v;
        if (scale) v *= scale[row];
        if (res) v += res[(size_t)row * ldres + col];
        if (Df) Df[(size_t)row * ldd + col] = v;
        if (Dhi) {
          short h = f2bf(v);
          Dhi[(size_t)row * lddp + col] = h;
          if (Dlo) Dlo[(size_t)row * lddp + col] = f2bf(v - bf2f(h));
        }
      }
    }
  }
}

// ---------------- GEMM v1: f32 inputs, in-staging conversion ----------------
// DEMUX: even rows -> Df f32 (row/2), odd rows -> Dhi/Dlo planes (row/2)
template<bool SPLIT, bool DEMUX>
__global__ __launch_bounds__(256, 2)
void g1_k(const float* __restrict__ A, int lda, long zsA,
          const float* __restrict__ W, int ldw, long zsB,
          const float* __restrict__ bias, int posbias,
          float* __restrict__ Df, short* __restrict__ Dhi, short* __restrict__ Dlo,
          int ldd, long zsD, int K)
{
  constexpr int NS = SPLIT ? 2 : 1;
  __shared__ short As[NS][128][40];
  __shared__ short Bs[NS][128][40];
  const long z = blockIdx.z;
  A += z * zsA; W += z * zsB;
  if (Df)  Df  += z * zsD;
  if (Dhi) Dhi += z * zsD;

  int bx, by; swz(bx, by);
  const int tid = threadIdx.x, lane = tid & 63, wid = tid >> 6;
  const int wr = wid >> 1, wc = wid & 1, fr = lane & 15, kg = lane >> 4;

  f4_t acc[4][4];
#pragma unroll
  for (int m = 0; m < 4; m++)
#pragma unroll
    for (int n = 0; n < 4; n++)
#pragma unroll
      for (int j = 0; j < 4; j++) acc[m][n][j] = 0.f;

  const int srow = tid >> 1, skoff = (tid & 1) << 4;
  const float* pA = A + (size_t)((size_t)by * 128 + srow) * lda + skoff;
  const float* pW = W + (size_t)((size_t)bx * 128 + srow) * ldw + skoff;

  for (int kb = 0; kb < K; kb += 32) {
    float va[16], vw[16];
    {
      const f4_t* a4 = (const f4_t*)(pA + kb);
      const f4_t* w4 = (const f4_t*)(pW + kb);
#pragma unroll
      for (int q = 0; q < 4; q++) {
        f4_t ta = a4[q], tw = w4[q];
#pragma unroll
        for (int j = 0; j < 4; j++) { va[q * 4 + j] = ta[j]; vw[q * 4 + j] = tw[j]; }
      }
    }
    __syncthreads();
#pragma unroll
    for (int h = 0; h < 2; h++) {
      bf8_t ha, hw;
#pragma unroll
      for (int j = 0; j < 8; j++) { ha[j] = f2bf(va[h * 8 + j]); hw[j] = f2bf(vw[h * 8 + j]); }
      *(bf8_t*)&As[0][srow][skoff + h * 8] = ha;
      *(bf8_t*)&Bs[0][srow][skoff + h * 8] = hw;
      if constexpr (SPLIT) {
        bf8_t la, lw;
#pragma unroll
        for (int j = 0; j < 8; j++) {
          la[j] = f2bf(va[h * 8 + j] - bf2f(ha[j]));
          lw[j] = f2bf(vw[h * 8 + j] - bf2f(hw[j]));
        }
        *(bf8_t*)&As[NS - 1][srow][skoff + h * 8] = la;
        *(bf8_t*)&Bs[NS - 1][srow][skoff + h * 8] = lw;
      }
    }
    __syncthreads();

    bf8_t a0[4], b0[4], a1[4], b1[4];
#pragma unroll
    for (int m = 0; m < 4; m++) {
      a0[m] = *(const bf8_t*)&As[0][wr * 64 + m * 16 + fr][kg * 8];
      if constexpr (SPLIT) a1[m] = *(const bf8_t*)&As[NS - 1][wr * 64 + m * 16 + fr][kg * 8];
    }
#pragma unroll
    for (int n = 0; n < 4; n++) {
      b0[n] = *(const bf8_t*)&Bs[0][wc * 64 + n * 16 + fr][kg * 8];
      if constexpr (SPLIT) b1[n] = *(const bf8_t*)&Bs[NS - 1][wc * 64 + n * 16 + fr][kg * 8];
    }
#pragma unroll
    for (int m = 0; m < 4; m++)
#pragma unroll
      for (int n = 0; n < 4; n++) {
        acc[m][n] = __builtin_amdgcn_mfma_f32_16x16x32_bf16(a0[m], b0[n], acc[m][n], 0, 0, 0);
        if constexpr (SPLIT) {
          acc[m][n] = __builtin_amdgcn_mfma_f32_16x16x32_bf16(a0[m], b1[n], acc[m][n], 0, 0, 0);
          acc[m][n] = __builtin_amdgcn_mfma_f32_16x16x32_bf16(a1[m], b0[n], acc[m][n], 0, 0, 0);
        }
      }
  }

  const int Ncols = (int)gridDim.x * 128;
#pragma unroll
  for (int m = 0; m < 4; m++) {
#pragma unroll
    for (int n = 0; n < 4; n++) {
      const int col = bx * 128 + wc * 64 + n * 16 + fr;
#pragma unroll
      for (int j = 0; j < 4; j++) {
        const int row = by * 128 + wr * 64 + m * 16 + kg * 4 + j;
        float v = acc[m][n][j];
        if (bias) v += bias[posbias ? ((row & 1) * Ncols + col) : col];
        if constexpr (DEMUX) {
          const size_t o = (size_t)(row >> 1) * ldd + col;
          if (row & 1) { short h = f2bf(v); Dhi[o] = h; Dlo[o] = f2bf(v - bf2f(h)); }
          else Df[o] = v;
        } else {
          if (Dhi) Dhi[(size_t)row * ldd + col] = f2bf(v);
          else     Df[(size_t)row * ldd + col] = v;
        }
      }
    }
  }
}

// ---------------- LayerNorm(512) -> bf16 hi/lo planes ----------------
__global__ __launch_bounds__(256)
void ln2_k(const float* __restrict__ x, int ldx,
           const float* __restrict__ s, const float* __restrict__ b,
           short* __restrict__ hi, short* __restrict__ lo, int ldy)
{
  const int lane = threadIdx.x & 63;
  const int row = blockIdx.x * 4 + (threadIdx.x >> 6);
  const float* xr = x + (size_t)row * ldx + lane * 8;
  f4_t v0 = *(const f4_t*)xr;
  f4_t v1 = *(const f4_t*)(xr + 4);
  float sum = (v0[0] + v0[1]) + (v0[2] + v0[3]) + ((v1[0] + v1[1]) + (v1[2] + v1[3]));
#pragma unroll
  for (int o = 32; o; o >>= 1) sum += __shfl_xor(sum, o, 64);
  const float mean = sum * (1.f / 512.f);
  float vs = 0.f;
#pragma unroll
  for (int j = 0; j < 4; j++) { float d0 = v0[j] - mean, d1 = v1[j] - mean; vs += d0 * d0 + d1 * d1; }
#pragma unroll
  for (int o = 32; o; o >>= 1) vs += __shfl_xor(vs, o, 64);
  const float rstd = rsqrtf(vs * (1.f / 512.f) + 1e-5f);
  const float* sp = s + lane * 8; const float* bp = b + lane * 8;
  bf8_t h, l;
#pragma unroll
  for (int j = 0; j < 4; j++) {
    float y0 = (v0[j] - mean) * rstd * sp[j] + bp[j];
    float y1 = (v1[j] - mean) * rstd * sp[j + 4] + bp[j + 4];
    short h0 = f2bf(y0); h[j] = h0;     l[j] = f2bf(y0 - bf2f(h0));
    short h1 = f2bf(y1); h[j + 4] = h1; l[j + 4] = f2bf(y1 - bf2f(h1));
  }
  *(bf8_t*)&hi[(size_t)row * ldy + lane * 8] = h;
  *(bf8_t*)&lo[(size_t)row * ldy + lane * 8] = l;
}

// ---------------- f32 -> bf16 hi(/lo) planes ----------------
__global__ __launch_bounds__(256)
void conv_k(const float* __restrict__ src, long zs, int ld, int cols,
            short* __restrict__ hi, short* __restrict__ lo, long dzs)
{
  const long z = blockIdx.z;
  int idx = blockIdx.x * 256 + threadIdx.x;
  int cpr = cols >> 3;
  int row = idx / cpr, c8 = (idx % cpr) << 3;
  const float* p = src + z * zs + (size_t)row * ld + c8;
  f4_t v0 = *(const f4_t*)p, v1 = *(const f4_t*)(p + 4);
  bf8_t h, l;
#pragma unroll
  for (int j = 0; j < 4; j++) {
    short h0 = f2bf(v0[j]); h[j] = h0;     l[j] = f2bf(v0[j] - bf2f(h0));
    short h1 = f2bf(v1[j]); h[j + 4] = h1; l[j + 4] = f2bf(v1[j] - bf2f(h1));
  }
  size_t dof = (size_t)z * dzs + (size_t)row * cols + c8;
  *(bf8_t*)&hi[dof] = h;
  if (lo) *(bf8_t*)&lo[dof] = l;
}

// ---------------- te3 transpose: (8,512o,512g) -> (8,512g,512o) ----------------
__global__ __launch_bounds__(256)
void tr_k(const float* __restrict__ in, float* __restrict__ out)
{
  __shared__ float t[32][33];
  const int e = blockIdx.z, ob = blockIdx.x * 32, gb = blockIdx.y * 32;
  const int tx = threadIdx.x & 31, ty = threadIdx.x >> 5;
  const float* I = in + ((size_t)e * 512 + ob) * 512 + gb;
  float* O = out + ((size_t)e * 512 + gb) * 512 + ob;
#pragma unroll
  for (int i = 0; i < 4; i++) t[ty + 8 * i][tx] = I[(size_t)(ty + 8 * i) * 512 + tx];
  __syncthreads();
#pragma unroll
  for (int i = 0; i < 4; i++) O[(size_t)(ty + 8 * i) * 512 + tx] = t[tx][ty + 8 * i];
}

// ---------------- bc[e][oo] = sum_o po_w[oo][512+512e+o] * te3_b[e][o] ----------------
__global__ __launch_bounds__(256)
void bc_k(const float* __restrict__ po, const float* __restrict__ te3b, float* __restrict__ bc)
{
  int idx = blockIdx.x * 256 + threadIdx.x;   // 4096
  int e = idx >> 9, oo = idx & 511;
  const float* p = po + (size_t)oo * 4608 + 512 + (size_t)e * 512;
  const float* tb = te3b + (size_t)e * 512;
  float s = 0.f;
#pragma unroll 4
  for (int g = 0; g < 512; g += 4) {
    f4_t a = *(const f4_t*)(p + g);
    f4_t b = *(const f4_t*)(tb + g);
    s += a[0] * b[0] + a[1] * b[1] + a[2] * b[2] + a[3] * b[3];
  }
  bc[idx] = s;
}

// ---------------- router: logits -> top-2 idx + gate vals (NO atomics) ----------------
__global__ __launch_bounds__(256)
void router_k(const float* __restrict__ R1, const float* __restrict__ r2w,
              const float* __restrict__ r2b, int2* __restrict__ ridx,
              float2* __restrict__ rgv)
{
  const int lane = threadIdx.x & 63;
  const int row = blockIdx.x * 4 + (threadIdx.x >> 6);
  f4_t xv = *(const f4_t*)(R1 + (size_t)row * 256 + lane * 4);
  float lg[8];
#pragma unroll
  for (int e = 0; e < 8; e++) {
    f4_t wv = *(const f4_t*)(r2w + e * 256 + lane * 4);
    float p = xv[0] * wv[0] + xv[1] * wv[1] + xv[2] * wv[2] + xv[3] * wv[3];
#pragma unroll
    for (int o = 32; o; o >>= 1) p += __shfl_xor(p, o, 64);
    lg[e] = p + r2b[e];
  }
  int i1 = 0; float v1 = lg[0];
#pragma unroll
  for (int e = 1; e < 8; e++) if (lg[e] > v1) { v1 = lg[e]; i1 = e; }
  int i2 = -1; float v2 = -3.4e38f;
#pragma unroll
  for (int e = 0; e < 8; e++) if (e != i1 && lg[e] > v2) { v2 = lg[e]; i2 = e; }
  const float p2 = 1.f / (1.f + expf(v1 - v2));
  const float p1 = 1.f - p2;
  if (lane == 0) {
    ridx[row] = make_int2(i1, i2);
    rgv[row] = make_float2(p1, p2);
  }
}

// ---------------- sched: count + offsets + scatter, single block, ballot-based ----------------
__global__ __launch_bounds__(1024, 1)
void sched_k(const int2* __restrict__ ridx, const float2* __restrict__ rgv,
             int* __restrict__ offs, int* __restrict__ perm,
             float* __restrict__ pgate, int2* __restrict__ islot)
{
  __shared__ int wcnt[16][8];
  __shared__ int wbase[16][8];
  __shared__ int soff[9];
  const int tid = threadIdx.x, lane = tid & 63, w = tid >> 6;
  const unsigned long long below = (lane == 63) ? 0x7FFFFFFFFFFFFFFFULL
                                                : ((1ULL << lane) - 1);
  // pass A: per-wave expert counts via uniform ballots
  int2 rid[8]; float2 rgl[8];
  int cnt[8];
#pragma unroll
  for (int e = 0; e < 8; e++) cnt[e] = 0;
#pragma unroll
  for (int it = 0; it < 8; it++) {
    int r = w * 512 + it * 64 + lane;
    rid[it] = ridx[r]; rgl[it] = rgv[r];
#pragma unroll
    for (int e = 0; e < 8; e++) {
      unsigned long long m0 = __ballot(rid[it].x == e);
      unsigned long long m1 = __ballot(rid[it].y == e);
      cnt[e] += (int)__popcll(m0) + (int)__popcll(m1);
    }
  }
  if (lane == 0) {
#pragma unroll
    for (int e = 0; e < 8; e++) wcnt[w][e] = cnt[e];
  }
  __syncthreads();
  // offsets (padded to 128) + per-wave bases
  if (tid == 0) {
    int a = 0; soff[0] = 0;
    for (int e = 0; e < 8; e++) {
      int run = a, tot = 0;
      for (int ww = 0; ww < 16; ww++) { wbase[ww][e] = run; run += wcnt[ww][e]; tot += wcnt[ww][e]; }
      a += (tot + 127) & ~127;
      soff[e + 1] = a;
    }
  }
  __syncthreads();
  if (tid < 9) offs[tid] = soff[tid];
  // fill all slots with pad defaults (pass B overwrites real ones)
  for (int i = tid; i < 17408; i += 1024) { perm[i] = -1; pgate[i] = 0.f; }
  __syncthreads();
  // pass B: rank-within-ballot scatter (same traversal order as pass A)
  int cur[8];
#pragma unroll
  for (int e = 0; e < 8; e++) cur[e] = wbase[w][e];
#pragma unroll
  for (int it = 0; it < 8; it++) {
    int r = w * 512 + it * 64 + lane;
    int p0 = 0, p1 = 0;
#pragma unroll
    for (int e = 0; e < 8; e++) {
      unsigned long long m = __ballot(rid[it].x == e);
      if (rid[it].x == e) p0 = cur[e] + (int)__popcll(m & below);
      cur[e] += (int)__popcll(m);
    }
#pragma unroll
    for (int e = 0; e < 8; e++) {
      unsigned long long m = __ballot(rid[it].y == e);
      if (rid[it].y == e) p1 = cur[e] + (int)__popcll(m & below);
      cur[e] += (int)__popcll(m);
    }
    perm[p0] = r; pgate[p0] = rgl[it].x;
    perm[p1] = r; pgate[p1] = rgl[it].y;
    islot[r] = make_int2(p0, p1);
  }
}

__global__ __launch_bounds__(256)
void fadd_k(const int2* __restrict__ islot, const float* __restrict__ EO, float* __restrict__ out)
{
  int idx = blockIdx.x * 256 + threadIdx.x;
  int r = idx >> 7, c4 = (idx & 127) << 2;
  int2 s = islot[r];
  f4_t a = *(const f4_t*)&EO[(size_t)s.x * 512 + c4];
  f4_t b = *(const f4_t*)&EO[(size_t)s.y * 512 + c4];
  float* op = &out[(size_t)r * 512 + c4];
  f4_t o = *(const f4_t*)op;
#pragma unroll
  for (int j = 0; j < 4; j++) o[j] += a[j] + b[j];
  *(f4_t*)op = o;
}

__global__ void bias2_k(const float* __restrict__ pib, const float* __restrict__ pos,
                        float* __restrict__ bias2)
{
  int i = blockIdx.x * 256 + threadIdx.x;
  if (i < 1024) bias2[i] = pib[i & 511] + pos[i];
}

// =====================================================================

extern "C" void kernel_launch(void* const* d_in, const int* in_sizes, int n_in,
                              void* d_out, int out_size, void* d_ws, size_t ws_size,
                              hipStream_t stream)
{
  (void)in_sizes; (void)n_in; (void)out_size; (void)ws_size;
  const float* src     = (const float*)d_in[0];
  const float* piw     = (const float*)d_in[1];
  const float* pib     = (const float*)d_in[2];
  const float* pos     = (const float*)d_in[3];
  const float* ln1_s   = (const float*)d_in[4];
  const float* ln1_b   = (const float*)d_in[5];
  // ln2 (d_in[6],[7]) dead: feeds only Q; softmax over 1 key == 1
  const float* ln3_s   = (const float*)d_in[8];
  const float* ln3_b   = (const float*)d_in[9];
  const float* sa_in_w = (const float*)d_in[10];
  const float* sa_in_b = (const float*)d_in[11];
  const float* sa_ow   = (const float*)d_in[12];
  const float* sa_ob   = (const float*)d_in[13];
  const float* ca_in_w = (const float*)d_in[14];
  const float* ca_in_b = (const float*)d_in[15];
  const float* ca_ow   = (const float*)d_in[16];
  const float* ca_ob   = (const float*)d_in[17];
  const float* ff1_w   = (const float*)d_in[18];
  const float* ff1_b   = (const float*)d_in[19];
  const float* ff2_w   = (const float*)d_in[20];
  const float* ff2_b   = (const float*)d_in[21];
  const float* r1_w    = (const float*)d_in[22];
  const float* r1_b    = (const float*)d_in[23];
  const float* r2_w    = (const float*)d_in[24];
  const float* r2_b    = (const float*)d_in[25];
  const float* se1_w   = (const float*)d_in[26];
  const float* se1_b   = (const float*)d_in[27];
  const float* se2_w   = (const float*)d_in[28];
  const float* se2_b   = (const float*)d_in[29];
  const float* se3_w   = (const float*)d_in[30];
  const float* se3_b   = (const float*)d_in[31];
  const float* te1_w   = (const float*)d_in[32];
  const float* te1_b   = (const float*)d_in[33];
  const float* te2_w   = (const float*)d_in[34];
  const float* te2_b   = (const float*)d_in[35];
  const float* te3_w   = (const float*)d_in[36];
  const float* te3_b   = (const float*)d_in[37];
  const float* po_w    = (const float*)d_in[38];
  const float* po_b    = (const float*)d_in[39];
  float* out = (float*)d_out;

  // ------------- arena (total ~134.1 MB <= proven 134.48 MB) -------------
  const size_t MiB = 1048576;
  char* base = (char*)d_ws;
  // loop phase
  float* tgt   = (float*)(base + 0 * MiB);    // 8192x512 f32, ld 512
  short* MemHi = (short*)(base + 16 * MiB);
  short* MemLo = (short*)(base + 24 * MiB);
  short* Hhi   = (short*)(base + 32 * MiB);
  short* Hlo   = (short*)(base + 40 * MiB);
  short* Fhi   = (short*)(base + 48 * MiB);   // 8192x2048
  short* Flo   = (short*)(base + 80 * MiB);
  short* Vhi   = (short*)(base + 48 * MiB);   // alias F (attn vs FFN disjoint)
  short* Vlo   = (short*)(base + 56 * MiB);
  // per-layer weight scratch [112,124)
  short* wsV   = (short*)(base + 112 * MiB);  // 8 planes of 512x512
  short* saVhi = wsV;             short* saVlo = wsV + 262144;
  short* saOhi = wsV + 524288;    short* saOlo = wsV + 786432;
  short* caVhi = wsV + 1048576;   short* caVlo = wsV + 1310720;
  short* caOhi = wsV + 1572864;   short* caOlo = wsV + 1835008;
  short* ff1hi = (short*)(base + 116 * MiB);  short* ff1lo = ff1hi + 1048576;
  short* ff2hi = (short*)(base + 120 * MiB);  short* ff2lo = ff2hi + 1048576;
  // head phase (aliases of dead loop regions)
  short* tgtHi = Hhi;  short* tgtLo = Hlo;            // written by last ff2
  float* te3T  = (float*)(base + 0 * MiB);            // 8 MiB, before S1
  short* S1hi  = (short*)(base + 0 * MiB);            // 8192x1024
  short* S2hi  = (short*)(base + 16 * MiB);
  short* SHhi  = (short*)(base + 24 * MiB);
  short* X1hi  = (short*)(base + 48 * MiB);           // 17408x1024 -> [48,82)
  short* X2hi  = (short*)(base + 82 * MiB);           // 17408x512  -> [82,99)
  float* EO    = (float*)(base + 48 * MiB);           // over dead X1
  float* F2    = (float*)(base + 104 * MiB);          // 8192x256 f32
  short* te1hi = (short*)(base + 104 * MiB);          // after router (F2 dead)
  short* te2hi = (short*)(base + 112 * MiB);          // over layer scratch
  short* Wchi  = (short*)(base + 120 * MiB);
  // persistent small region @124MiB
  char*  ps    = base + 124 * MiB;
  size_t cur = 0;
  auto alloc = [&](size_t bytes) { char* r = ps + cur; cur = (cur + bytes + 255) & ~(size_t)255; return r; };
  float*  bias2 = (float*)alloc(1024 * 4);
  float*  bc    = (float*)alloc(4096 * 4);
  int*    offs  = (int*)  alloc(64 * 4);
  int2*   ridx  = (int2*) alloc(8192 * 8);
  float2* rgv   = (float2*)alloc(8192 * 8);
  int2*   islot = (int2*) alloc(8192 * 8);
  int*    perm  = (int*)  alloc(17408 * 4);
  float*  pgate = (float*)alloc(17408 * 4);
  short*  r1hi  = (short*)alloc(524288);  short* r1lo = r1hi + 131072;
  short*  se1hi = (short*)alloc(1048576);
  short*  se2hi = (short*)alloc(1048576);
  short*  se3hi = (short*)alloc(524288);
  short*  pomhi = (short*)alloc(524288);

  auto conv = [&](const float* s_, long zs, int ld, int rows, int cols, int z,
                  short* hi, short* lo, long dzs) {
    conv_k<<<dim3(rows * cols / 2048, 1, z), dim3(256), 0, stream>>>(s_, zs, ld, cols, hi, lo, dzs);
  };

  // ---------------- pre-phase ----------------
  bias2_k<<<dim3(4), dim3(256), 0, stream>>>(pib, pos, bias2);
  conv(r1_w, 0, 512, 256, 512, 1, r1hi, r1lo, 0);
  conv(se1_w, 0, 512, 1024, 512, 1, se1hi, nullptr, 0);
  conv(se2_w, 0, 1024, 512, 1024, 1, se2hi, nullptr, 0);
  conv(se3_w, 0, 512, 512, 512, 1, se3hi, nullptr, 0);
  conv(po_w, 0, 4608, 512, 512, 1, pomhi, nullptr, 0);
  bc_k<<<dim3(16), dim3(256), 0, stream>>>(po_w, te3_b, bc);

  // input proj: even rows -> tgt f32, odd rows -> Mem planes (DEMUX)
  g1_k<true, true><<<dim3(4, 128, 1), dim3(256), 0, stream>>>(
      src, 512, 0, piw, 512, 0, bias2, 1, tgt, MemHi, MemLo, 512, 0, 512);

  // ---------------- trunk loop ----------------
  for (int i = 0; i < 6; i++) {
    conv(sa_in_w + (size_t)i * 786432 + 524288, 0, 512, 512, 512, 1, saVhi, saVlo, 0);
    conv(sa_ow + (size_t)i * 262144, 0, 512, 512, 512, 1, saOhi, saOlo, 0);
    conv(ca_in_w + (size_t)i * 786432 + 524288, 0, 512, 512, 512, 1, caVhi, caVlo, 0);
    conv(ca_ow + (size_t)i * 262144, 0, 512, 512, 512, 1, caOhi, caOlo, 0);
    conv(ff1_w + (size_t)i * 1048576, 0, 512, 2048, 512, 1, ff1hi, ff1lo, 0);
    conv(ff2_w + (size_t)i * 1048576, 0, 2048, 512, 2048, 1, ff2hi, ff2lo, 0);

    ln2_k<<<dim3(2048), dim3(256), 0, stream>>>(tgt, 512, ln1_s + i * 512, ln1_b + i * 512, Hhi, Hlo, 512);
    g2_k<64, 128, true, 0, 0, 4><<<dim3(4, 128), 256, 0, stream>>>(
        Hhi, Hlo, 512, saVhi, saVlo, 512, 0, sa_in_b + i * 1536 + 1024, 0,
        nullptr, 0, nullptr, nullptr, 0, Vhi, Vlo, 512, nullptr, nullptr, 512);
    g2_k<64, 128, true, 0, 0, 4><<<dim3(4, 128), 256, 0, stream>>>(
        Vhi, Vlo, 512, saOhi, saOlo, 512, 0, sa_ob + i * 512, 0,
        tgt, 512, nullptr, tgt, 512, nullptr, nullptr, 0, nullptr, nullptr, 512);
    g2_k<64, 128, true, 0, 0, 4><<<dim3(4, 128), 256, 0, stream>>>(
        MemHi, MemLo, 512, caVhi, caVlo, 512, 0, ca_in_b + i * 1536 + 1024, 0,
        nullptr, 0, nullptr, nullptr, 0, Vhi, Vlo, 512, nullptr, nullptr, 512);
    g2_k<64, 128, true, 0, 0, 4><<<dim3(4, 128), 256, 0, stream>>>(
        Vhi, Vlo, 512, caOhi, caOlo, 512, 0, ca_ob + i * 512, 0,
        tgt, 512, nullptr, tgt, 512, nullptr, nullptr, 0, nullptr, nullptr, 512);
    ln2_k<<<dim3(2048), dim3(256), 0, stream>>>(tgt, 512, ln3_s + i * 512, ln3_b + i * 512, Hhi, Hlo, 512);
    g2_k<128, 128, true, 1, 0, 3><<<dim3(16, 64), 256, 0, stream>>>(
        Hhi, Hlo, 512, ff1hi, ff1lo, 512, 0, ff1_b + i * 2048, 0,
        nullptr, 0, nullptr, nullptr, 0, Fhi, Flo, 2048, nullptr, nullptr, 512);
    bool last = (i == 5);
    g2_k<64, 128, true, 0, 0, 4><<<dim3(4, 128), 256, 0, stream>>>(
        Fhi, Flo, 2048, ff2hi, ff2lo, 2048, 0, ff2_b + i * 512, 0,
        tgt, 512, nullptr, tgt, 512,
        last ? tgtHi : nullptr, last ? tgtLo : nullptr, 512, nullptr, nullptr, 2048);
  }

  // ---------------- router (atomic-free) ----------------
  g2_k<64, 128, true, 2, 0, 4><<<dim3(2, 128), 256, 0, stream>>>(
      tgtHi, tgtLo, 512, r1hi, r1lo, 512, 0, r1_b, 0,
      nullptr, 0, nullptr, F2, 256, nullptr, nullptr, 0, nullptr, nullptr, 512);
  router_k<<<dim3(2048), dim3(256), 0, stream>>>(F2, r2_w, r2_b, ridx, rgv);
  sched_k<<<dim3(1), dim3(1024), 0, stream>>>(ridx, rgv, offs, perm, pgate, islot);

  // ---------------- fused te3*po precompute (Wc) + expert-weight planes ----------------
  tr_k<<<dim3(16, 16, 8), dim3(256), 0, stream>>>(te3_w, te3T);
  g1_k<false, false><<<dim3(4, 4, 8), dim3(256), 0, stream>>>(
      po_w + 512, 4608, 512, te3T, 512, 262144,
      nullptr, 0, nullptr, Wchi, nullptr, 512, 262144, 512);
  conv(te1_w, 524288, 512, 1024, 512, 8, te1hi, nullptr, 524288);   // over dead F2
  conv(te2_w, 524288, 1024, 512, 1024, 8, te2hi, nullptr, 524288);  // over dead layer scratch

  // ---------------- shared head ----------------
  g2_k<128, 128, false, 2, 0, 3><<<dim3(8, 64), 256, 0, stream>>>(
      tgtHi, nullptr, 512, se1hi, nullptr, 512, 0, se1_b, 0,
      nullptr, 0, nullptr, nullptr, 0, S1hi, nullptr, 1024, nullptr, nullptr, 512);
  g2_k<64, 128, false, 2, 0, 4><<<dim3(4, 128), 256, 0, stream>>>(
      S1hi, nullptr, 1024, se2hi, nullptr, 1024, 0, se2_b, 0,
      nullptr, 0, nullptr, nullptr, 0, S2hi, nullptr, 512, nullptr, nullptr, 1024);
  g2_k<64, 128, false, 0, 0, 4><<<dim3(4, 128), 256, 0, stream>>>(
      S2hi, nullptr, 512, se3hi, nullptr, 512, 0, se3_b, 0,
      nullptr, 0, nullptr, nullptr, 0, SHhi, nullptr, 512, nullptr, nullptr, 512);
  g2_k<64, 128, false, 0, 0, 4><<<dim3(4, 128), 256, 0, stream>>>(
      SHhi, nullptr, 512, pomhi, nullptr, 512, 0, po_b, 0,
      nullptr, 0, nullptr, out, 512, nullptr, nullptr, 0, nullptr, nullptr, 512);

  // ---------------- sparse experts (top-2) ----------------
  g2_k<128, 128, false, 2, 2, 3><<<dim3(8, 136), 256, 0, stream>>>(
      tgtHi, nullptr, 512, te1hi, nullptr, 512, 524288, te1_b, 1024,
      nullptr, 0, nullptr, nullptr, 0, X1hi, nullptr, 1024, offs, perm, 512);
  g2_k<64, 128, false, 2, 1, 4><<<dim3(4, 272), 256, 0, stream>>>(
      X1hi, nullptr, 1024, te2hi, nullptr, 1024, 524288, te2_b, 512,
      nullptr, 0, nullptr, nullptr, 0, X2hi, nullptr, 512, offs, nullptr, 1024);
  g2_k<64, 128, false, 0, 1, 4><<<dim3(4, 272), 256, 0, stream>>>(
      X2hi, nullptr, 512, Wchi, nullptr, 512, 262144, bc, 512,
      nullptr, 0, pgate, EO, 512, nullptr, nullptr, 0, offs, nullptr, 512);
  fadd_k<<<dim3(4096), dim3(256), 0, stream>>>(islot, EO, out);
}